// Round 4
// baseline (5804.295 us; speedup 1.0000x reference)
//
#include <hip/hip_runtime.h>
#include <hip/hip_bf16.h>
#include <math.h>

#define S_LEN 8192
#define D_MODEL 768
#define D_RNN 1024
#define MLP_INNER 3072

#define BM 64
#define BN 64
#define BK 16

__device__ __forceinline__ float gelu_tanh(float v) {
    float c = 0.7978845608028654f; // sqrt(2/pi)
    float t = tanhf(c * (v + 0.044715f * v * v * v));
    return 0.5f * v * (1.0f + t);
}

__device__ __forceinline__ float sigmoidf_(float v) {
    return 1.0f / (1.0f + expf(-v));
}

// ---------------------------------------------------------------------------
// RMSNorm: one block per row
// ---------------------------------------------------------------------------
__global__ __launch_bounds__(256) void rms_kernel(const float* __restrict__ x,
                                                  const float* __restrict__ w,
                                                  float* __restrict__ o, int D) {
    int row = blockIdx.x;
    const float* xr = x + (size_t)row * D;
    float ss = 0.0f;
    for (int i = threadIdx.x; i < D; i += 256) {
        float v = xr[i];
        ss += v * v;
    }
    for (int off = 32; off > 0; off >>= 1) ss += __shfl_down(ss, off);
    __shared__ float wsum[4];
    __shared__ float sc;
    int lane = threadIdx.x & 63, wid = threadIdx.x >> 6;
    if (lane == 0) wsum[wid] = ss;
    __syncthreads();
    if (threadIdx.x == 0) {
        float t = wsum[0] + wsum[1] + wsum[2] + wsum[3];
        sc = rsqrtf(t / (float)D + 1e-5f);
    }
    __syncthreads();
    float s = sc;
    float* orow = o + (size_t)row * D;
    for (int i = threadIdx.x; i < D; i += 256) orow[i] = xr[i] * s * w[i];
}

// ---------------------------------------------------------------------------
// Tiled fp32 GEMM:  C[M,N] = A[M,K] * B[N,K]^T + bias + resid   (fp32 out)
// AMODE 0: plain A.  AMODE 1: A[m,k] = gelu(A[m*2048+k]) * A2[m*1024+k]
// ---------------------------------------------------------------------------
template <int AMODE>
__global__ __launch_bounds__(256) void gemm_nt(const float* __restrict__ A,
                                               const float* __restrict__ A2,
                                               const float* __restrict__ B,
                                               const float* __restrict__ bias,
                                               const float* __restrict__ resid,
                                               float* __restrict__ C,
                                               int M, int N, int K) {
    __shared__ float As[BK][BM + 1];
    __shared__ float Bs[BK][BN + 1];
    int tid = threadIdx.x;
    int tx = tid & 15, ty = tid >> 4;
    int m0 = blockIdx.y * BM, n0 = blockIdx.x * BN;
    int lk = tid & 15, lr = tid >> 4;
    float acc[4][4] = {};
    for (int k0 = 0; k0 < K; k0 += BK) {
#pragma unroll
        for (int r = 0; r < 4; r++) {
            int row = lr + 16 * r;
            int gm = m0 + row;
            int k = k0 + lk;
            float av;
            if (AMODE == 0) {
                av = A[(size_t)gm * K + k];
            } else {
                av = gelu_tanh(A[((size_t)gm << 11) + k]) * A2[((size_t)gm << 10) + k];
            }
            As[lk][row] = av;
            Bs[lk][row] = B[(size_t)(n0 + row) * K + k];
        }
        __syncthreads();
#pragma unroll
        for (int kk = 0; kk < BK; kk++) {
            float ar[4], br[4];
#pragma unroll
            for (int i = 0; i < 4; i++) ar[i] = As[kk][ty * 4 + i];
#pragma unroll
            for (int j = 0; j < 4; j++) br[j] = Bs[kk][tx * 4 + j];
#pragma unroll
            for (int i = 0; i < 4; i++)
#pragma unroll
                for (int j = 0; j < 4; j++) acc[i][j] += ar[i] * br[j];
        }
        __syncthreads();
    }
#pragma unroll
    for (int i = 0; i < 4; i++) {
        int m = m0 + ty * 4 + i;
#pragma unroll
        for (int j = 0; j < 4; j++) {
            int n = n0 + tx * 4 + j;
            float v = acc[i][j];
            if (bias) v += bias[n];
            if (resid) v += resid[(size_t)m * N + n];
            C[(size_t)m * N + n] = v;
        }
    }
}

// ---------------------------------------------------------------------------
// Conv-as-GEMM with fused im2col. N=1024, K=4096.
//   A[t, i2*4+dk] = (t+dk-3 >= 0) ? ab[t+dk-3, 1024+i2] : 0
// ---------------------------------------------------------------------------
__global__ __launch_bounds__(256) void gemm_conv(const float* __restrict__ ab,
                                                 const float* __restrict__ Bw,
                                                 float* __restrict__ C, int M) {
    const int K = 4096, N = 1024;
    __shared__ float As[BK][BM + 1];
    __shared__ float Bs[BK][BN + 1];
    int tid = threadIdx.x;
    int tx = tid & 15, ty = tid >> 4;
    int m0 = blockIdx.y * BM, n0 = blockIdx.x * BN;
    int lk = tid & 15, lr = tid >> 4;
    float acc[4][4] = {};
    for (int k0 = 0; k0 < K; k0 += BK) {
#pragma unroll
        for (int r = 0; r < 4; r++) {
            int row = lr + 16 * r;
            int kk = k0 + lk;
            int i2 = kk >> 2, dk = kk & 3;
            int s = m0 + row + dk - 3;
            As[lk][row] = (s >= 0) ? ab[((size_t)s << 11) + 1024 + i2] : 0.0f;
            Bs[lk][row] = Bw[(size_t)(n0 + row) * K + kk];
        }
        __syncthreads();
#pragma unroll
        for (int kk = 0; kk < BK; kk++) {
            float ar[4], br[4];
#pragma unroll
            for (int i = 0; i < 4; i++) ar[i] = As[kk][ty * 4 + i];
#pragma unroll
            for (int j = 0; j < 4; j++) br[j] = Bs[kk][tx * 4 + j];
#pragma unroll
            for (int i = 0; i < 4; i++)
#pragma unroll
                for (int j = 0; j < 4; j++) acc[i][j] += ar[i] * br[j];
        }
        __syncthreads();
    }
#pragma unroll
    for (int i = 0; i < 4; i++) {
        int m = m0 + ty * 4 + i;
#pragma unroll
        for (int j = 0; j < 4; j++) {
            int n = n0 + tx * 4 + j;
            C[(size_t)m * N + n] = acc[i][j];
        }
    }
}

// ---------------------------------------------------------------------------
// Dual-B GEMM for gates + fused gate math. N'=1024, K=1024.
// ---------------------------------------------------------------------------
__global__ __launch_bounds__(256) void gemm_gates(const float* __restrict__ Ac,
                                                  const float* __restrict__ Bw,
                                                  const float* __restrict__ bias,
                                                  const float* __restrict__ nl,
                                                  float* __restrict__ a_o,
                                                  float* __restrict__ gx_o, int M) {
    const int K = 1024;
    __shared__ float As[BK][BM + 1];
    __shared__ float B1s[BK][BN + 1];
    __shared__ float B2s[BK][BN + 1];
    int tid = threadIdx.x;
    int tx = tid & 15, ty = tid >> 4;
    int m0 = blockIdx.y * BM, n0 = blockIdx.x * BN;
    int lk = tid & 15, lr = tid >> 4;
    float acc1[4][4] = {}, acc2[4][4] = {};
    for (int k0 = 0; k0 < K; k0 += BK) {
#pragma unroll
        for (int r = 0; r < 4; r++) {
            int row = lr + 16 * r;
            int k = k0 + lk;
            As[lk][row] = Ac[(size_t)(m0 + row) * K + k];
            B1s[lk][row] = Bw[(size_t)(n0 + row) * K + k];
            B2s[lk][row] = Bw[(size_t)(n0 + row + 1024) * K + k];
        }
        __syncthreads();
#pragma unroll
        for (int kk = 0; kk < BK; kk++) {
            float ar[4], b1[4], b2[4];
#pragma unroll
            for (int i = 0; i < 4; i++) ar[i] = As[kk][ty * 4 + i];
#pragma unroll
            for (int j = 0; j < 4; j++) { b1[j] = B1s[kk][tx * 4 + j]; b2[j] = B2s[kk][tx * 4 + j]; }
#pragma unroll
            for (int i = 0; i < 4; i++)
#pragma unroll
                for (int j = 0; j < 4; j++) {
                    acc1[i][j] += ar[i] * b1[j];
                    acc2[i][j] += ar[i] * b2[j];
                }
        }
        __syncthreads();
    }
#pragma unroll
    for (int i = 0; i < 4; i++) {
        int m = m0 + ty * 4 + i;
#pragma unroll
        for (int j = 0; j < 4; j++) {
            int n = n0 + tx * 4 + j;
            float ig = sigmoidf_(acc1[i][j] + bias[n]);
            float rg = sigmoidf_(acc2[i][j] + bias[1024 + n]);
            float av = expf(nl[n] * rg);
            size_t id = ((size_t)m << 10) + n;
            a_o[id] = av;
            gx_o[id] = sqrtf(fmaxf(1.0f - av * av, 0.0f)) * ig * Ac[id];
        }
    }
}

// ---------------------------------------------------------------------------
// Dual-B GEMM for MLP up-proj + GeGLU. N'=3072, K=768.
// ---------------------------------------------------------------------------
__global__ __launch_bounds__(256) void gemm_geglu(const float* __restrict__ Ah,
                                                  const float* __restrict__ Bw,
                                                  const float* __restrict__ bias,
                                                  float* __restrict__ g, int M) {
    const int K = 768;
    __shared__ float As[BK][BM + 1];
    __shared__ float B1s[BK][BN + 1];
    __shared__ float B2s[BK][BN + 1];
    int tid = threadIdx.x;
    int tx = tid & 15, ty = tid >> 4;
    int m0 = blockIdx.y * BM, n0 = blockIdx.x * BN;
    int lk = tid & 15, lr = tid >> 4;
    float acc1[4][4] = {}, acc2[4][4] = {};
    for (int k0 = 0; k0 < K; k0 += BK) {
#pragma unroll
        for (int r = 0; r < 4; r++) {
            int row = lr + 16 * r;
            int k = k0 + lk;
            As[lk][row] = Ah[(size_t)(m0 + row) * K + k];
            B1s[lk][row] = Bw[(size_t)(n0 + row) * K + k];
            B2s[lk][row] = Bw[(size_t)(n0 + row + MLP_INNER) * K + k];
        }
        __syncthreads();
#pragma unroll
        for (int kk = 0; kk < BK; kk++) {
            float ar[4], b1[4], b2[4];
#pragma unroll
            for (int i = 0; i < 4; i++) ar[i] = As[kk][ty * 4 + i];
#pragma unroll
            for (int j = 0; j < 4; j++) { b1[j] = B1s[kk][tx * 4 + j]; b2[j] = B2s[kk][tx * 4 + j]; }
#pragma unroll
            for (int i = 0; i < 4; i++)
#pragma unroll
                for (int j = 0; j < 4; j++) {
                    acc1[i][j] += ar[i] * b1[j];
                    acc2[i][j] += ar[i] * b2[j];
                }
        }
        __syncthreads();
    }
#pragma unroll
    for (int i = 0; i < 4; i++) {
        int m = m0 + ty * 4 + i;
#pragma unroll
        for (int j = 0; j < 4; j++) {
            int n = n0 + tx * 4 + j;
            float v1 = gelu_tanh(acc1[i][j] + bias[n]);
            float v2 = acc2[i][j] + bias[MLP_INNER + n];
            g[(size_t)m * MLP_INNER + n] = v1 * v2;
        }
    }
}

// ---------------------------------------------------------------------------
__global__ void nl_kernel(const float* __restrict__ Lambda, float* __restrict__ nl) {
    int c = blockIdx.x * 256 + threadIdx.x;
    if (c < D_RNN) nl[c] = -8.0f * log1pf(expf(Lambda[c]));
}

// ---------------------------------------------------------------------------
// Linear recurrence (in-place safe: y aliases gx)
// ---------------------------------------------------------------------------
__global__ __launch_bounds__(256) void scan_kernel(const float* __restrict__ a,
                                                   const float* __restrict__ gx,
                                                   float* __restrict__ y) {
    int c = blockIdx.x * 256 + threadIdx.x; // 1024 channels
    float state = 0.0f;
    for (int t = 0; t < S_LEN; t++) {
        size_t id = ((size_t)t << 10) + c;
        state = fmaf(a[id], state, gx[id]);
        y[id] = state;
    }
}

// ---------------------------------------------------------------------------
extern "C" void kernel_launch(void* const* d_in, const int* in_sizes, int n_in,
                              void* d_out, int out_size, void* d_ws, size_t ws_size,
                              hipStream_t stream) {
    const float* x      = (const float*)d_in[0];
    const float* w_n1   = (const float*)d_in[1];
    const float* w_n2   = (const float*)d_in[2];
    const float* w_lin1 = (const float*)d_in[3];
    const float* b_lin1 = (const float*)d_in[4];
    const float* w_conv = (const float*)d_in[5];
    const float* w_rg   = (const float*)d_in[6];
    const float* b_rg   = (const float*)d_in[7];
    const float* Lambda = (const float*)d_in[8];
    const float* w_out  = (const float*)d_in[9];
    const float* b_out  = (const float*)d_in[10];
    const float* w_m1   = (const float*)d_in[11];
    const float* b_m1   = (const float*)d_in[12];
    const float* w_m2   = (const float*)d_in[13];
    const float* b_m2   = (const float*)d_in[14];

    char* ws = (char*)d_ws;
    const size_t MB = 1024ull * 1024ull;
    // Footprint: 160 MB + 4 KB. Lifetimes strictly sequential:
    //   [0,64)    ab                 -> g [0,96) after step 7
    //   [64,88)   h (rms1)           -> [64,96) conv after step 2
    //   [96,128)  a                  -> [96,120) x1 after scan
    //   [128,160) gx / y (in-place)  -> [128,152) h2 after step 7
    //   [160MB)   nl (4 KB)
    float* ab   = (float*)(ws + 0);
    float* h    = (float*)(ws + 64 * MB);
    float* conv = (float*)(ws + 64 * MB);
    float* a_b  = (float*)(ws + 96 * MB);
    float* x1   = (float*)(ws + 96 * MB);
    float* gx   = (float*)(ws + 128 * MB);
    float* y    = gx; // in-place scan
    float* h2   = (float*)(ws + 128 * MB);
    float* g    = (float*)(ws + 0);
    float* nl   = (float*)(ws + 160 * MB);
    float* out  = (float*)d_out;  // fp32 output (reference returns float32)

    const int M = S_LEN;

    // 1. h = rms(x, w_n1)
    rms_kernel<<<M, 256, 0, stream>>>(x, w_n1, h, D_MODEL);
    // 2. ab = h @ w_lin1^T + b_lin1   (N=2048, K=768)
    gemm_nt<0><<<dim3(2048 / BN, M / BM), 256, 0, stream>>>(
        h, nullptr, w_lin1, b_lin1, nullptr, ab, M, 2048, 768);
    // 3. conv = im2col(ab[:,1024:]) @ w_conv^T  (N=1024, K=4096)
    gemm_conv<<<dim3(1024 / BN, M / BM), 256, 0, stream>>>(ab, w_conv, conv, M);
    // 4. nl = -8*softplus(Lambda)
    nl_kernel<<<4, 256, 0, stream>>>(Lambda, nl);
    // 5. gates GEMM + gate math -> a, gx   (N'=1024, K=1024)
    gemm_gates<<<dim3(1024 / BN, M / BM), 256, 0, stream>>>(
        conv, w_rg, b_rg, nl, a_b, gx, M);
    // 6. scan (in-place: y aliases gx)
    scan_kernel<<<4, 256, 0, stream>>>(a_b, gx, y);
    // 7. x1 = (gelu(ab[:,:1024])*y) @ w_out^T + b_out + x   (N=768, K=1024)
    gemm_nt<1><<<dim3(768 / BN, M / BM), 256, 0, stream>>>(
        ab, y, w_out, b_out, x, x1, M, 768, 1024);
    // 8. h2 = rms(x1, w_n2)
    rms_kernel<<<M, 256, 0, stream>>>(x1, w_n2, h2, D_MODEL);
    // 9. MLP up-proj + GeGLU -> g   (N'=3072, K=768)
    gemm_geglu<<<dim3(3072 / BN, M / BM), 256, 0, stream>>>(h2, w_m1, b_m1, g, M);
    // 10. out = g @ w_m2^T + b_m2 + x1   (N=768, K=3072, fp32 store)
    gemm_nt<0><<<dim3(768 / BN, M / BM), 256, 0, stream>>>(
        g, nullptr, w_m2, b_m2, x1, out, M, 768, 3072);
}

// Round 5
// 2247.197 us; speedup vs baseline: 2.5829x; 2.5829x over previous
//
#include <hip/hip_runtime.h>
#include <hip/hip_bf16.h>
#include <math.h>

#define S_LEN 8192
#define D_MODEL 768
#define D_RNN 1024
#define MLP_INNER 3072

typedef __attribute__((ext_vector_type(8))) short bf16x8;
typedef __attribute__((ext_vector_type(4))) float f32x4;
typedef unsigned short ushort_t;

__device__ __forceinline__ float gelu_tanh(float v) {
    float c = 0.7978845608028654f; // sqrt(2/pi)
    float t = tanhf(c * (v + 0.044715f * v * v * v));
    return 0.5f * v * (1.0f + t);
}
__device__ __forceinline__ float sigmoidf_(float v) { return 1.0f / (1.0f + expf(-v)); }
__device__ __forceinline__ float us2f(ushort_t u) { return __uint_as_float(((unsigned)u) << 16); }
__device__ __forceinline__ ushort_t f2us(float f) {
    __hip_bfloat16 b = __float2bfloat16(f);
    return *(ushort_t*)&b;
}

// ---------------------------------------------------------------------------
// Weight conversion fp32 -> bf16
// ---------------------------------------------------------------------------
__global__ __launch_bounds__(256) void cvt_w(const float* __restrict__ src,
                                             ushort_t* __restrict__ dst, int n) {
    int i = blockIdx.x * 256 + threadIdx.x;
    if (i < n) dst[i] = f2us(src[i]);
}

// w_conv (O=1024, I=1024, H=4) -> wb[o, dk*1024 + i] = w_conv[o*4096 + i*4 + dk]
__global__ __launch_bounds__(256) void cvt_wconv(const float* __restrict__ src,
                                                 ushort_t* __restrict__ dst) {
    int d = blockIdx.x * 256 + threadIdx.x; // 4194304
    int i2 = d & 1023, dk = (d >> 10) & 3, o = d >> 12;
    dst[d] = f2us(src[(size_t)o * 4096 + i2 * 4 + dk]);
}

// ---------------------------------------------------------------------------
// RMSNorm fp32 in -> bf16 out
// ---------------------------------------------------------------------------
__global__ __launch_bounds__(256) void rms_kernel(const float* __restrict__ x,
                                                  const float* __restrict__ w,
                                                  ushort_t* __restrict__ o, int D) {
    int row = blockIdx.x;
    const float* xr = x + (size_t)row * D;
    float ss = 0.0f;
    for (int i = threadIdx.x; i < D; i += 256) { float v = xr[i]; ss += v * v; }
    for (int off = 32; off > 0; off >>= 1) ss += __shfl_down(ss, off);
    __shared__ float wsum[4];
    __shared__ float sc;
    int lane = threadIdx.x & 63, wid = threadIdx.x >> 6;
    if (lane == 0) wsum[wid] = ss;
    __syncthreads();
    if (threadIdx.x == 0) {
        float t = wsum[0] + wsum[1] + wsum[2] + wsum[3];
        sc = rsqrtf(t / (float)D + 1e-5f);
    }
    __syncthreads();
    float s = sc;
    ushort_t* orow = o + (size_t)row * D;
    for (int i = threadIdx.x; i < D; i += 256) orow[i] = f2us(xr[i] * s * w[i]);
}

// ---------------------------------------------------------------------------
// MFMA bf16 NT GEMM: C[M,N] = A[M,K] @ B[N,K]^T (+bias)(+resid)
// 128x128 tile, 4 waves, each 64x64 (4x4 of 16x16x32 MFMA), BK=32.
// AMODE 0: A = Abf[M,K] bf16 row-major
// AMODE 1: A[m,k] = gelu(ab_a16[m*1024+k]) * y[m*1024+k]    (K==1024)
// AMODE 2: A[m,k] = gelu(m16[m*6144+k]) * m16[m*6144+3072+k] (K==3072)
// EMODE 0: bf16 -> Cb[M,N]
// EMODE 1: split: n<1024 -> Cb[m*1024+n], else Cb2[m*1024+n-1024]  (bf16)
// EMODE 2: fp32 + resid -> Cf[M,N]
// ---------------------------------------------------------------------------
template <int AMODE, int EMODE>
__global__ __launch_bounds__(256) void mfma_nt(const ushort_t* __restrict__ Abf,
                                               const float* __restrict__ Af32,
                                               const ushort_t* __restrict__ Bbf,
                                               const float* __restrict__ bias,
                                               const float* __restrict__ resid,
                                               float* __restrict__ Cf,
                                               ushort_t* __restrict__ Cb,
                                               ushort_t* __restrict__ Cb2,
                                               int M, int N, int K) {
    __shared__ ushort_t As[128 * 32];
    __shared__ ushort_t Bs[128 * 32];
    int tid = threadIdx.x;
    int wave = tid >> 6, lane = tid & 63;
    int quad = lane >> 4, l16 = lane & 15;
    int wm = (wave >> 1) * 64, wn = (wave & 1) * 64;
    int m0 = blockIdx.y * 128, n0 = blockIdx.x * 128;
    int r = tid >> 2, c = (tid & 3) * 8; // staging: row r/r+64, k-cols c..c+7

    f32x4 acc[4][4] = {};

    for (int k0 = 0; k0 < K; k0 += 32) {
        // ---- stage A (rows r and r+64) ----
        if (AMODE == 0) {
            const ushort_t* a0 = Abf + (size_t)(m0 + r) * K + k0 + c;
            *(uint4*)&As[r * 32 + c] = *(const uint4*)a0;
            *(uint4*)&As[(r + 64) * 32 + c] = *(const uint4*)(a0 + (size_t)64 * K);
        } else if (AMODE == 1) {
#pragma unroll
            for (int h = 0; h < 2; h++) {
                int gm = m0 + r + h * 64;
                int gk = k0 + c;
                const ushort_t* pa = Abf + ((size_t)gm << 10) + gk;
                const float* py = Af32 + ((size_t)gm << 10) + gk;
                ushort_t tmp[8];
#pragma unroll
                for (int u = 0; u < 8; u++)
                    tmp[u] = f2us(gelu_tanh(us2f(pa[u])) * py[u]);
                *(uint4*)&As[(r + h * 64) * 32 + c] = *(uint4*)tmp;
            }
        } else {
#pragma unroll
            for (int h = 0; h < 2; h++) {
                int gm = m0 + r + h * 64;
                int gk = k0 + c;
                const ushort_t* pm = Abf + (size_t)gm * 6144 + gk;
                ushort_t tmp[8];
#pragma unroll
                for (int u = 0; u < 8; u++)
                    tmp[u] = f2us(gelu_tanh(us2f(pm[u])) * us2f(pm[3072 + u]));
                *(uint4*)&As[(r + h * 64) * 32 + c] = *(uint4*)tmp;
            }
        }
        // ---- stage B ----
        {
            const ushort_t* b0 = Bbf + (size_t)(n0 + r) * K + k0 + c;
            *(uint4*)&Bs[r * 32 + c] = *(const uint4*)b0;
            *(uint4*)&Bs[(r + 64) * 32 + c] = *(const uint4*)(b0 + (size_t)64 * K);
        }
        __syncthreads();
        // ---- fragments + MFMA ----
        bf16x8 af[4], bfr[4];
#pragma unroll
        for (int i = 0; i < 4; i++)
            af[i] = *(const bf16x8*)&As[(wm + i * 16 + l16) * 32 + quad * 8];
#pragma unroll
        for (int j = 0; j < 4; j++)
            bfr[j] = *(const bf16x8*)&Bs[(wn + j * 16 + l16) * 32 + quad * 8];
#pragma unroll
        for (int i = 0; i < 4; i++)
#pragma unroll
            for (int j = 0; j < 4; j++)
                acc[i][j] = __builtin_amdgcn_mfma_f32_16x16x32_bf16(af[i], bfr[j],
                                                                   acc[i][j], 0, 0, 0);
        __syncthreads();
    }

    // ---- epilogue: C/D layout col=lane&15, row=quad*4+reg ----
#pragma unroll
    for (int i = 0; i < 4; i++) {
        int mbase = m0 + wm + i * 16 + quad * 4;
#pragma unroll
        for (int j = 0; j < 4; j++) {
            int n = n0 + wn + j * 16 + l16;
            float bv = bias ? bias[n] : 0.0f;
#pragma unroll
            for (int rg = 0; rg < 4; rg++) {
                int m = mbase + rg;
                float v = acc[i][j][rg] + bv;
                if (EMODE == 0) {
                    Cb[(size_t)m * N + n] = f2us(v);
                } else if (EMODE == 1) {
                    if (n < 1024) Cb[((size_t)m << 10) + n] = f2us(v);
                    else          Cb2[((size_t)m << 10) + (n - 1024)] = f2us(v);
                } else {
                    float o = v + (resid ? resid[(size_t)m * N + n] : 0.0f);
                    Cf[(size_t)m * N + n] = o;
                }
            }
        }
    }
}

// ---------------------------------------------------------------------------
// A2[t, dk*1024 + i] = (t+dk-3 >= 0) ? ab_b16[t+dk-3, i] : 0
// ---------------------------------------------------------------------------
__global__ __launch_bounds__(256) void build_a2(const ushort_t* __restrict__ abb,
                                                ushort_t* __restrict__ A2) {
    int idx = blockIdx.x * 256 + threadIdx.x; // S*4096
    int i2 = idx & 1023, dk = (idx >> 10) & 3, t = idx >> 12;
    int s = t + dk - 3;
    A2[idx] = (s >= 0) ? abb[((size_t)s << 10) + i2] : (ushort_t)0;
}

// ---------------------------------------------------------------------------
__global__ void nl_kernel(const float* __restrict__ Lambda, float* __restrict__ nl) {
    int c = blockIdx.x * 256 + threadIdx.x;
    if (c < D_RNN) nl[c] = -8.0f * log1pf(expf(Lambda[c]));
}

// ---------------------------------------------------------------------------
// gates16 [S,2048] bf16 (pre-activations incl. bias), conv16 [S,1024] bf16
// -> a fp32, gx fp32
// ---------------------------------------------------------------------------
__global__ __launch_bounds__(256) void gate_ew(const ushort_t* __restrict__ gates16,
                                               const ushort_t* __restrict__ conv16,
                                               const float* __restrict__ nl,
                                               float* __restrict__ a_o,
                                               float* __restrict__ gx_o) {
    int idx = blockIdx.x * 256 + threadIdx.x; // S*1024
    int n = idx & 1023;
    int s = idx >> 10;
    float ig = sigmoidf_(us2f(gates16[((size_t)s << 11) + n]));
    float rg = sigmoidf_(us2f(gates16[((size_t)s << 11) + 1024 + n]));
    float av = expf(nl[n] * rg);
    a_o[idx] = av;
    gx_o[idx] = sqrtf(fmaxf(1.0f - av * av, 0.0f)) * ig * us2f(conv16[idx]);
}

// ---------------------------------------------------------------------------
// Linear recurrence (in-place: y aliases gx)
// ---------------------------------------------------------------------------
__global__ __launch_bounds__(256) void scan_kernel(const float* __restrict__ a,
                                                   const float* __restrict__ gx,
                                                   float* __restrict__ y) {
    int c = blockIdx.x * 256 + threadIdx.x; // 1024 channels
    float state = 0.0f;
    for (int t = 0; t < S_LEN; t++) {
        size_t id = ((size_t)t << 10) + c;
        state = fmaf(a[id], state, gx[id]);
        y[id] = state;
    }
}

// ---------------------------------------------------------------------------
extern "C" void kernel_launch(void* const* d_in, const int* in_sizes, int n_in,
                              void* d_out, int out_size, void* d_ws, size_t ws_size,
                              hipStream_t stream) {
    const float* x      = (const float*)d_in[0];
    const float* w_n1   = (const float*)d_in[1];
    const float* w_n2   = (const float*)d_in[2];
    const float* w_lin1 = (const float*)d_in[3];
    const float* b_lin1 = (const float*)d_in[4];
    const float* w_conv = (const float*)d_in[5];
    const float* w_rg   = (const float*)d_in[6];
    const float* b_rg   = (const float*)d_in[7];
    const float* Lambda = (const float*)d_in[8];
    const float* w_out  = (const float*)d_in[9];
    const float* b_out  = (const float*)d_in[10];
    const float* w_m1   = (const float*)d_in[11];
    const float* b_m1   = (const float*)d_in[12];
    const float* w_m2   = (const float*)d_in[13];
    const float* b_m2   = (const float*)d_in[14];

    char* ws = (char*)d_ws;
    const size_t MB = 1024ull * 1024ull;
    // Peak footprint 197 MB (ws >= 208 MB proven safe in round 1).
    // [0,32)   wb (bf16 weights, persistent)
    // [32,56)  x1 fp32 (persistent from out-proj on)
    // [56,+4K) nl
    // [57,69)  h16        -> h2_16 later
    // [69,85)  ab_a16     -> m16 [69,165) later
    // [85,101) ab_b16     -> conv16 later
    // [101,165) A2        -> gates16 [101,133), a [133,165) later
    // [165,197) gx / y (in-place scan)
    ushort_t* wb   = (ushort_t*)(ws + 0);
    float*    x1   = (float*)(ws + 32 * MB);
    float*    nl   = (float*)(ws + 56 * MB);
    ushort_t* h16  = (ushort_t*)(ws + 57 * MB);
    ushort_t* h2   = (ushort_t*)(ws + 57 * MB);
    ushort_t* aba  = (ushort_t*)(ws + 69 * MB);
    ushort_t* m16  = (ushort_t*)(ws + 69 * MB);
    ushort_t* abb  = (ushort_t*)(ws + 85 * MB);
    ushort_t* cv16 = (ushort_t*)(ws + 85 * MB);
    ushort_t* A2   = (ushort_t*)(ws + 101 * MB);
    ushort_t* gt16 = (ushort_t*)(ws + 101 * MB);
    float*    a_b  = (float*)(ws + 133 * MB);
    float*    gx   = (float*)(ws + 165 * MB);
    float*    y    = gx;
    float*    out  = (float*)d_out;

    // bf16 weight blocks (element offsets in wb)
    ushort_t* wb_lin1 = wb + 0;          // 2048*768
    ushort_t* wb_conv = wb + 1572864;    // 1024*4096 (reordered)
    ushort_t* wb_rg   = wb + 5767168;    // 2048*1024
    ushort_t* wb_out  = wb + 7864320;    // 768*1024
    ushort_t* wb_m1   = wb + 8650752;    // 6144*768
    ushort_t* wb_m2   = wb + 13369344;   // 768*3072

    const int M = S_LEN;

    // 0. weight conversion
    cvt_w<<<(1572864 + 255) / 256, 256, 0, stream>>>(w_lin1, wb_lin1, 1572864);
    cvt_wconv<<<4194304 / 256, 256, 0, stream>>>(w_conv, wb_conv);
    cvt_w<<<(2097152 + 255) / 256, 256, 0, stream>>>(w_rg, wb_rg, 2097152);
    cvt_w<<<(786432 + 255) / 256, 256, 0, stream>>>(w_out, wb_out, 786432);
    cvt_w<<<(4718592 + 255) / 256, 256, 0, stream>>>(w_m1, wb_m1, 4718592);
    cvt_w<<<(2359296 + 255) / 256, 256, 0, stream>>>(w_m2, wb_m2, 2359296);
    nl_kernel<<<4, 256, 0, stream>>>(Lambda, nl);

    // 1. h = rms(x, w_n1) -> bf16
    rms_kernel<<<M, 256, 0, stream>>>(x, w_n1, h16, D_MODEL);
    // 2. ab = h @ w_lin1^T + b_lin1 -> split ab_a16 / ab_b16   (N=2048, K=768)
    mfma_nt<0, 1><<<dim3(2048 / 128, M / 128), 256, 0, stream>>>(
        h16, nullptr, wb_lin1, b_lin1, nullptr, nullptr, aba, abb, M, 2048, 768);
    // 3. A2 = im2col(ab_b16)
    build_a2<<<(M * 4096) / 256, 256, 0, stream>>>(abb, A2);
    // 4. conv = A2 @ wb_conv^T -> bf16   (N=1024, K=4096)
    mfma_nt<0, 0><<<dim3(1024 / 128, M / 128), 256, 0, stream>>>(
        A2, nullptr, wb_conv, nullptr, nullptr, nullptr, cv16, nullptr, M, 1024, 4096);
    // 5. gates = conv @ w_rg^T + b_rg -> bf16   (N=2048, K=1024)
    mfma_nt<0, 0><<<dim3(2048 / 128, M / 128), 256, 0, stream>>>(
        cv16, nullptr, wb_rg, b_rg, nullptr, nullptr, gt16, nullptr, M, 2048, 1024);
    // 6. gate math -> a, gx
    gate_ew<<<(M * 1024) / 256, 256, 0, stream>>>(gt16, cv16, nl, a_b, gx);
    // 7. scan (in-place)
    scan_kernel<<<4, 256, 0, stream>>>(a_b, gx, y);
    // 8. x1 = (gelu(ab_a)*y) @ w_out^T + b_out + x   (N=768, K=1024, fp32)
    mfma_nt<1, 2><<<dim3(768 / 128, M / 128), 256, 0, stream>>>(
        aba, y, wb_out, b_out, x, x1, nullptr, nullptr, M, 768, 1024);
    // 9. h2 = rms(x1, w_n2) -> bf16
    rms_kernel<<<M, 256, 0, stream>>>(x1, w_n2, h2, D_MODEL);
    // 10. m = h2 @ w_m1^T + b_m1 -> bf16   (N=6144, K=768)
    mfma_nt<0, 0><<<dim3(6144 / 128, M / 128), 256, 0, stream>>>(
        h2, nullptr, wb_m1, b_m1, nullptr, nullptr, m16, nullptr, M, 6144, 768);
    // 11. out = (gelu(m1)*m2) @ w_m2^T + b_m2 + x1   (N=768, K=3072, fp32)
    mfma_nt<2, 2><<<dim3(768 / 128, M / 128), 256, 0, stream>>>(
        m16, nullptr, wb_m2, b_m2, x1, out, nullptr, nullptr, M, 768, 3072);
}

// Round 6
// 727.881 us; speedup vs baseline: 7.9742x; 3.0873x over previous
//
#include <hip/hip_runtime.h>
#include <hip/hip_bf16.h>
#include <math.h>

#define S_LEN 8192
#define D_MODEL 768
#define D_RNN 1024
#define MLP_INNER 3072

typedef __attribute__((ext_vector_type(8))) short bf16x8;
typedef __attribute__((ext_vector_type(4))) float f32x4;
typedef unsigned short ushort_t;

#ifndef __has_builtin
#define __has_builtin(x) 0
#endif
#if __has_builtin(__builtin_amdgcn_global_load_lds)
#define HAS_ASYNC 1
#else
#define HAS_ASYNC 0
#endif

__device__ __forceinline__ float gelu_tanh(float v) {
    float c = 0.7978845608028654f; // sqrt(2/pi)
    float t = tanhf(c * (v + 0.044715f * v * v * v));
    return 0.5f * v * (1.0f + t);
}
__device__ __forceinline__ float sigmoidf_(float v) { return 1.0f / (1.0f + expf(-v)); }
__device__ __forceinline__ float us2f(ushort_t u) { return __uint_as_float(((unsigned)u) << 16); }
__device__ __forceinline__ ushort_t f2us(float f) {
    __hip_bfloat16 b = __float2bfloat16(f);
    return *(ushort_t*)&b;
}

// async 16B global -> LDS (wave-uniform LDS base; HW adds lane*16B)
__device__ __forceinline__ void cp16(const ushort_t* g, ushort_t* l) {
#if HAS_ASYNC
    __builtin_amdgcn_global_load_lds((__attribute__((address_space(1))) void*)g,
                                     (__attribute__((address_space(3))) void*)l,
                                     16, 0, 0);
#endif
}

// ---------------------------------------------------------------------------
// Weight conversion fp32 -> bf16
// ---------------------------------------------------------------------------
__global__ __launch_bounds__(256) void cvt_w(const float* __restrict__ src,
                                             ushort_t* __restrict__ dst, int n) {
    int i = blockIdx.x * 256 + threadIdx.x;
    if (i < n) dst[i] = f2us(src[i]);
}

// w_conv (O=1024, I=1024, H=4) -> wb[o, dk*1024 + i] = w_conv[o*4096 + i*4 + dk]
__global__ __launch_bounds__(256) void cvt_wconv(const float* __restrict__ src,
                                                 ushort_t* __restrict__ dst) {
    int d = blockIdx.x * 256 + threadIdx.x; // 4194304
    int i2 = d & 1023, dk = (d >> 10) & 3, o = d >> 12;
    dst[d] = f2us(src[(size_t)o * 4096 + i2 * 4 + dk]);
}

// ---------------------------------------------------------------------------
// RMSNorm fp32 in -> bf16 out
// ---------------------------------------------------------------------------
__global__ __launch_bounds__(256) void rms_kernel(const float* __restrict__ x,
                                                  const float* __restrict__ w,
                                                  ushort_t* __restrict__ o, int D) {
    int row = blockIdx.x;
    const float* xr = x + (size_t)row * D;
    float ss = 0.0f;
    for (int i = threadIdx.x; i < D; i += 256) { float v = xr[i]; ss += v * v; }
    for (int off = 32; off > 0; off >>= 1) ss += __shfl_down(ss, off);
    __shared__ float wsum[4];
    __shared__ float sc;
    int lane = threadIdx.x & 63, wid = threadIdx.x >> 6;
    if (lane == 0) wsum[wid] = ss;
    __syncthreads();
    if (threadIdx.x == 0) {
        float t = wsum[0] + wsum[1] + wsum[2] + wsum[3];
        sc = rsqrtf(t / (float)D + 1e-5f);
    }
    __syncthreads();
    float s = sc;
    ushort_t* orow = o + (size_t)row * D;
    for (int i = threadIdx.x; i < D; i += 256) orow[i] = f2us(xr[i] * s * w[i]);
}

// ---------------------------------------------------------------------------
// MFMA bf16 NT GEMM, 128xBN_ tile, 4 waves (2x2), BK=32.
// AMODE 0: A[M,K] bf16 row-major.
// AMODE 1: conv im2col: A = abb base, element (m, k) = abb[(m + k/1024 - 3), k%1024]
//          == linear load at (m0+r-3)*1024 + k, guarded for m0==0.
// EMODE 0: bf16 -> Cb[M,N]
// EMODE 1: +bias, split halves -> Cb (n<1024), Cb2 (n>=1024), stride 1024
// EMODE 2: +bias +resid -> fp32 Cf[M,N]
// EMODE 3: dual-B gates: a=exp(nl*sig(acc2+b2)); gx=sqrt(1-a^2)*sig(acc1+b1)*cv
// EMODE 4: dual-B geglu: Cb[m*3072+n] = gelu(acc1+b1)*(acc2+b2)
// ---------------------------------------------------------------------------
template <int BN_, int AMODE, int EMODE>
__global__ __launch_bounds__(256) void mfma_nt(const ushort_t* __restrict__ A,
                                               const ushort_t* __restrict__ B,
                                               const ushort_t* __restrict__ B2,
                                               const float* __restrict__ bias,
                                               const float* __restrict__ bias2,
                                               const float* __restrict__ resid,
                                               const float* __restrict__ nl,
                                               const ushort_t* __restrict__ cv,
                                               float* __restrict__ Cf,
                                               float* __restrict__ Cf2,
                                               ushort_t* __restrict__ Cb,
                                               ushort_t* __restrict__ Cb2,
                                               int M, int N, int K) {
    constexpr bool DUAL = (EMODE == 3 || EMODE == 4);
    constexpr int NT = BN_ / 32;           // n-tiles per wave
    __shared__ ushort_t As[128 * 32];
    __shared__ ushort_t Bs[BN_ * 32];
    __shared__ ushort_t B2s[DUAL ? BN_ * 32 : 8];

    int tid = threadIdx.x;
    int wave = tid >> 6, lane = tid & 63;
    int quad = lane >> 4, l16 = lane & 15;
    int wm = (wave >> 1) * 64, wn = (wave & 1) * (BN_ / 2);
    int m0 = blockIdx.y * 128, n0 = blockIdx.x * BN_;
    int r4 = tid >> 2;          // staging row 0..63
    int c8 = (tid & 3) * 8;     // staging k-offset

    // global staging base pointers (element offsets; add k0 per iter)
    const ushort_t* gA0;
    if (AMODE == 0) gA0 = A + (size_t)(m0 + r4) * K + c8;
    else            gA0 = A + ((size_t)(m0 + r4) - 3) * 1024 + c8; // shifted conv base
    const ushort_t* gA1 = gA0 + (size_t)64 * (AMODE == 0 ? K : 1024);
    const ushort_t* gB0 = B + (size_t)(n0 + r4) * K + c8;
    const ushort_t* gB1 = gB0 + (size_t)64 * K;
    const ushort_t* gB2 = DUAL ? (B2 + (size_t)(n0 + r4) * K + c8) : nullptr;

    f32x4 acc[4][NT] = {};
    f32x4 acc2[DUAL ? 4 : 1][DUAL ? NT : 1] = {};

    for (int k0 = 0; k0 < K; k0 += 32) {
        // ---- stage A ----
        bool conv_guard = (AMODE == 1) && (m0 == 0);
#if HAS_ASYNC
        if (!conv_guard) {
            cp16(gA0 + k0, &As[wave * 512]);
            cp16(gA1 + k0, &As[wave * 512 + 2048]);
        } else
#endif
        {
            if (AMODE == 1 && m0 == 0) {
                int kglob = k0 + c8;
                int dk = kglob >> 10, ii = kglob & 1023;
                uint4 v0 = {0, 0, 0, 0};
                if (r4 + dk >= 3)
                    v0 = *(const uint4*)(A + (size_t)(r4 + dk - 3) * 1024 + ii);
                *(uint4*)&As[8 * tid] = v0;
                *(uint4*)&As[8 * tid + 2048] =
                    *(const uint4*)(A + (size_t)(r4 + 64 + dk - 3) * 1024 + ii);
            } else {
                *(uint4*)&As[8 * tid] = *(const uint4*)(gA0 + k0);
                *(uint4*)&As[8 * tid + 2048] = *(const uint4*)(gA1 + k0);
            }
        }
        // ---- stage B ----
#if HAS_ASYNC
        cp16(gB0 + k0, &Bs[wave * 512]);
        if (BN_ == 128) cp16(gB1 + k0, &Bs[wave * 512 + 2048]);
        if constexpr (DUAL) cp16(gB2 + k0, &B2s[wave * 512]);
#else
        *(uint4*)&Bs[8 * tid] = *(const uint4*)(gB0 + k0);
        if (BN_ == 128) *(uint4*)&Bs[8 * tid + 2048] = *(const uint4*)(gB1 + k0);
        if constexpr (DUAL) *(uint4*)&B2s[8 * tid] = *(const uint4*)(gB2 + k0);
#endif
        __syncthreads();
        // ---- fragments + MFMA ----
        bf16x8 af[4], bfv[NT], bf2v[NT];
#pragma unroll
        for (int i = 0; i < 4; i++)
            af[i] = *(const bf16x8*)&As[(wm + i * 16 + l16) * 32 + quad * 8];
#pragma unroll
        for (int j = 0; j < NT; j++) {
            bfv[j] = *(const bf16x8*)&Bs[(wn + j * 16 + l16) * 32 + quad * 8];
            if constexpr (DUAL)
                bf2v[j] = *(const bf16x8*)&B2s[(wn + j * 16 + l16) * 32 + quad * 8];
        }
#pragma unroll
        for (int i = 0; i < 4; i++)
#pragma unroll
            for (int j = 0; j < NT; j++) {
                acc[i][j] = __builtin_amdgcn_mfma_f32_16x16x32_bf16(af[i], bfv[j],
                                                                   acc[i][j], 0, 0, 0);
                if constexpr (DUAL)
                    acc2[i][j] = __builtin_amdgcn_mfma_f32_16x16x32_bf16(af[i], bf2v[j],
                                                                        acc2[i][j], 0, 0, 0);
            }
        __syncthreads();
    }

    // ---- epilogue: C/D layout col=lane&15, row=quad*4+reg ----
#pragma unroll
    for (int i = 0; i < 4; i++) {
        int mb = m0 + wm + i * 16 + quad * 4;
#pragma unroll
        for (int j = 0; j < NT; j++) {
            int n = n0 + wn + j * 16 + l16;
#pragma unroll
            for (int rg = 0; rg < 4; rg++) {
                int m = mb + rg;
                float v = acc[i][j][rg];
                if constexpr (EMODE == 0) {
                    Cb[(size_t)m * N + n] = f2us(v);
                } else if constexpr (EMODE == 1) {
                    v += bias[n];
                    if (n < 1024) Cb[((size_t)m << 10) + n] = f2us(v);
                    else          Cb2[((size_t)m << 10) + (n - 1024)] = f2us(v);
                } else if constexpr (EMODE == 2) {
                    v += bias[n];
                    if (resid) v += resid[(size_t)m * N + n];
                    Cf[(size_t)m * N + n] = v;
                } else if constexpr (EMODE == 3) {
                    float ig = sigmoidf_(v + bias[n]);
                    float rgv = sigmoidf_(acc2[i][j][rg] + bias2[n]);
                    float av = expf(nl[n] * rgv);
                    size_t id = ((size_t)m << 10) + n;
                    Cf[id] = av;
                    Cf2[id] = sqrtf(fmaxf(1.0f - av * av, 0.0f)) * ig * us2f(cv[id]);
                } else { // EMODE 4
                    float v1 = gelu_tanh(v + bias[n]);
                    float v2 = acc2[i][j][rg] + bias2[n];
                    Cb[(size_t)m * 3072 + n] = f2us(v1 * v2);
                }
            }
        }
    }
}

// ---------------------------------------------------------------------------
__global__ void nl_kernel(const float* __restrict__ Lambda, float* __restrict__ nl) {
    int c = blockIdx.x * 256 + threadIdx.x;
    if (c < D_RNN) nl[c] = -8.0f * log1pf(expf(Lambda[c]));
}

// ---------------------------------------------------------------------------
// Chunked linear scan: h_t = a_t*h_{t-1} + gx_t, 64 chunks x 128 steps.
// ---------------------------------------------------------------------------
#define NCHUNK 64
#define CHLEN 128

__global__ __launch_bounds__(256) void scan_pass1(const float* __restrict__ a,
                                                  const float* __restrict__ gx,
                                                  float* __restrict__ Ac,
                                                  float* __restrict__ Bc) {
    int g = blockIdx.x * 256 + threadIdx.x; // 65536
    int ch = g & 1023, ck = g >> 10;
    float P = 1.0f, Bv = 0.0f;
    size_t base = (((size_t)ck * CHLEN) << 10) + ch;
#pragma unroll 8
    for (int t = 0; t < CHLEN; t++) {
        float av = a[base + ((size_t)t << 10)];
        float bv = gx[base + ((size_t)t << 10)];
        P *= av;
        Bv = av * Bv + bv;
    }
    Ac[ck * 1024 + ch] = P;
    Bc[ck * 1024 + ch] = Bv;
}

__global__ __launch_bounds__(256) void scan_pass2(const float* __restrict__ Ac,
                                                  const float* __restrict__ Bc,
                                                  float* __restrict__ Hc) {
    int ch = blockIdx.x * 256 + threadIdx.x; // 1024
    float H = 0.0f;
#pragma unroll 8
    for (int j = 0; j < NCHUNK; j++) {
        Hc[j * 1024 + ch] = H;
        H = Ac[j * 1024 + ch] * H + Bc[j * 1024 + ch];
    }
}

__global__ __launch_bounds__(256) void scan_pass3(const float* __restrict__ a,
                                                  const float* __restrict__ gx,
                                                  const float* __restrict__ Hc,
                                                  float* __restrict__ y) {
    int g = blockIdx.x * 256 + threadIdx.x;
    int ch = g & 1023, ck = g >> 10;
    float state = Hc[ck * 1024 + ch];
    size_t base = (((size_t)ck * CHLEN) << 10) + ch;
#pragma unroll 8
    for (int t = 0; t < CHLEN; t++) {
        size_t id = base + ((size_t)t << 10);
        state = fmaf(a[id], state, gx[id]);
        y[id] = state;
    }
}

// ---------------------------------------------------------------------------
// z = gelu(ab_a) * y -> bf16
// ---------------------------------------------------------------------------
__global__ __launch_bounds__(256) void zbuild(const ushort_t* __restrict__ aba,
                                              const float* __restrict__ y,
                                              ushort_t* __restrict__ z) {
    int idx = blockIdx.x * 256 + threadIdx.x; // S*1024
    z[idx] = f2us(gelu_tanh(us2f(aba[idx])) * y[idx]);
}

// ---------------------------------------------------------------------------
extern "C" void kernel_launch(void* const* d_in, const int* in_sizes, int n_in,
                              void* d_out, int out_size, void* d_ws, size_t ws_size,
                              hipStream_t stream) {
    const float* x      = (const float*)d_in[0];
    const float* w_n1   = (const float*)d_in[1];
    const float* w_n2   = (const float*)d_in[2];
    const float* w_lin1 = (const float*)d_in[3];
    const float* b_lin1 = (const float*)d_in[4];
    const float* w_conv = (const float*)d_in[5];
    const float* w_rg   = (const float*)d_in[6];
    const float* b_rg   = (const float*)d_in[7];
    const float* Lambda = (const float*)d_in[8];
    const float* w_out  = (const float*)d_in[9];
    const float* b_out  = (const float*)d_in[10];
    const float* w_m1   = (const float*)d_in[11];
    const float* b_m1   = (const float*)d_in[12];
    const float* w_m2   = (const float*)d_in[13];
    const float* b_m2   = (const float*)d_in[14];

    char* ws = (char*)d_ws;
    const size_t MB = 1024ull * 1024ull;
    // Peak footprint 182 MB (<208 proven safe).
    // [0,32)    wb bf16 weights (persistent)
    // [32,56)   x1 fp32
    // [56,+4K)  nl
    // [57,69)   h16 / h2
    // [69,85)   aba (dead after zbuild)
    // [85,101)  abb (dead after conv) -> z (after scan)
    // [101,117) cv16 (dead after gates epilogue... kept through gate EMODE3 read)
    // [117,149) a_b fp32 (dead after scan) -> gm[117,165) (after x1 GEMM)
    // [149,181) gx / y fp32 in-place (dead after zbuild)
    // [181,182) Ac, Bc, Hc (256 KB each)
    ushort_t* wb   = (ushort_t*)(ws + 0);
    float*    x1   = (float*)(ws + 32 * MB);
    float*    nl   = (float*)(ws + 56 * MB);
    ushort_t* h16  = (ushort_t*)(ws + 57 * MB);
    ushort_t* aba  = (ushort_t*)(ws + 69 * MB);
    ushort_t* abb  = (ushort_t*)(ws + 85 * MB);
    ushort_t* z16  = (ushort_t*)(ws + 85 * MB);
    ushort_t* cv16 = (ushort_t*)(ws + 101 * MB);
    float*    a_b  = (float*)(ws + 117 * MB);
    ushort_t* gm   = (ushort_t*)(ws + 117 * MB);
    float*    gx   = (float*)(ws + 149 * MB);
    float*    y    = gx; // in-place pass3
    float*    Ac   = (float*)(ws + 181 * MB);
    float*    Bc   = (float*)(ws + 181 * MB + 262144);
    float*    Hc   = (float*)(ws + 181 * MB + 524288);
    float*    out  = (float*)d_out;

    ushort_t* wb_lin1 = wb + 0;          // 2048*768
    ushort_t* wb_conv = wb + 1572864;    // 1024*4096 (reordered)
    ushort_t* wb_rg   = wb + 5767168;    // 2048*1024
    ushort_t* wb_out  = wb + 7864320;    // 768*1024
    ushort_t* wb_m1   = wb + 8650752;    // 6144*768
    ushort_t* wb_m2   = wb + 13369344;   // 768*3072

    const int M = S_LEN;

    // 0. weight conversion + nl
    cvt_w<<<(1572864 + 255) / 256, 256, 0, stream>>>(w_lin1, wb_lin1, 1572864);
    cvt_wconv<<<4194304 / 256, 256, 0, stream>>>(w_conv, wb_conv);
    cvt_w<<<(2097152 + 255) / 256, 256, 0, stream>>>(w_rg, wb_rg, 2097152);
    cvt_w<<<(786432 + 255) / 256, 256, 0, stream>>>(w_out, wb_out, 786432);
    cvt_w<<<(4718592 + 255) / 256, 256, 0, stream>>>(w_m1, wb_m1, 4718592);
    cvt_w<<<(2359296 + 255) / 256, 256, 0, stream>>>(w_m2, wb_m2, 2359296);
    nl_kernel<<<4, 256, 0, stream>>>(Lambda, nl);

    // 1. h = rms(x, w_n1)
    rms_kernel<<<M, 256, 0, stream>>>(x, w_n1, h16, D_MODEL);
    // 2. ab = h @ w_lin1^T + b_lin1, split -> aba/abb  (N=2048, K=768)
    mfma_nt<128, 0, 1><<<dim3(2048 / 128, M / 128), 256, 0, stream>>>(
        h16, wb_lin1, nullptr, b_lin1, nullptr, nullptr, nullptr, nullptr,
        nullptr, nullptr, aba, abb, M, 2048, 768);
    // 3. conv = im2col(abb) @ wb_conv^T -> cv16  (N=1024, K=4096, fused gather)
    mfma_nt<128, 1, 0><<<dim3(1024 / 128, M / 128), 256, 0, stream>>>(
        abb, wb_conv, nullptr, nullptr, nullptr, nullptr, nullptr, nullptr,
        nullptr, nullptr, cv16, nullptr, M, 1024, 4096);
    // 4. dual-B gates GEMM + gate math -> a_b, gx  (N'=1024, K=1024)
    mfma_nt<64, 0, 3><<<dim3(1024 / 64, M / 128), 256, 0, stream>>>(
        cv16, wb_rg, wb_rg + 1024 * 1024, b_rg, b_rg + 1024, nullptr, nl, cv16,
        a_b, gx, nullptr, nullptr, M, 1024, 1024);
    // 5. chunked scan -> y (in-place on gx)
    scan_pass1<<<256, 256, 0, stream>>>(a_b, gx, Ac, Bc);
    scan_pass2<<<4, 256, 0, stream>>>(Ac, Bc, Hc);
    scan_pass3<<<256, 256, 0, stream>>>(a_b, gx, Hc, y);
    // 6. z = gelu(aba) * y -> bf16
    zbuild<<<(M * 1024) / 256, 256, 0, stream>>>(aba, y, z16);
    // 7. x1 = z @ w_out^T + b_out + x  (N=768, K=1024, fp32)
    mfma_nt<64, 0, 2><<<dim3(768 / 64, M / 128), 256, 0, stream>>>(
        z16, wb_out, nullptr, b_out, nullptr, x, nullptr, nullptr,
        x1, nullptr, nullptr, nullptr, M, 768, 1024);
    // 8. h2 = rms(x1, w_n2)
    rms_kernel<<<M, 256, 0, stream>>>(x1, w_n2, h16, D_MODEL);
    // 9. dual-B MLP up-proj + GeGLU -> gm bf16  (N'=3072, K=768)
    mfma_nt<64, 0, 4><<<dim3(3072 / 64, M / 128), 256, 0, stream>>>(
        h16, wb_m1, wb_m1 + 3072 * 768, b_m1, b_m1 + 3072, nullptr, nullptr, nullptr,
        nullptr, nullptr, gm, nullptr, M, 3072, 768);
    // 10. out = gm @ w_m2^T + b_m2 + x1  (N=768, K=3072, fp32)
    mfma_nt<64, 0, 2><<<dim3(768 / 64, M / 128), 256, 0, stream>>>(
        gm, wb_m2, nullptr, b_m2, nullptr, x1, nullptr, nullptr,
        out, nullptr, nullptr, nullptr, M, 768, 3072);
}

// Round 8
// 699.408 us; speedup vs baseline: 8.2989x; 1.0407x over previous
//
#include <hip/hip_runtime.h>
#include <hip/hip_bf16.h>
#include <math.h>

#define S_LEN 8192
#define D_MODEL 768
#define D_RNN 1024
#define MLP_INNER 3072

typedef __attribute__((ext_vector_type(8))) short bf16x8;
typedef __attribute__((ext_vector_type(4))) float f32x4;
typedef unsigned short ushort_t;

#ifndef __has_builtin
#define __has_builtin(x) 0
#endif
#if __has_builtin(__builtin_amdgcn_global_load_lds)
#define HAS_ASYNC 1
#else
#define HAS_ASYNC 0
#endif

__device__ __forceinline__ float gelu_tanh(float v) {
    float c = 0.7978845608028654f; // sqrt(2/pi)
    float t = tanhf(c * (v + 0.044715f * v * v * v));
    return 0.5f * v * (1.0f + t);
}
__device__ __forceinline__ float sigmoidf_(float v) { return 1.0f / (1.0f + expf(-v)); }
__device__ __forceinline__ float us2f(ushort_t u) { return __uint_as_float(((unsigned)u) << 16); }
__device__ __forceinline__ ushort_t f2us(float f) {
    __hip_bfloat16 b = __float2bfloat16(f);
    return *(ushort_t*)&b;
}

// async 16B global -> LDS (wave-uniform LDS base; HW adds lane*16B)
__device__ __forceinline__ void cp16(const ushort_t* g, ushort_t* l) {
#if HAS_ASYNC
    __builtin_amdgcn_global_load_lds((__attribute__((address_space(1))) void*)g,
                                     (__attribute__((address_space(3))) void*)l,
                                     16, 0, 0);
#endif
}

// ---------------------------------------------------------------------------
// One-shot weight conversion fp32 -> bf16 (all weights) + nl
// ---------------------------------------------------------------------------
__global__ __launch_bounds__(256) void cvt_all(const float* __restrict__ w_lin1,
                                               const float* __restrict__ w_conv,
                                               const float* __restrict__ w_rg,
                                               const float* __restrict__ w_out,
                                               const float* __restrict__ w_m1,
                                               const float* __restrict__ w_m2,
                                               const float* __restrict__ Lambda,
                                               ushort_t* __restrict__ wb,
                                               float* __restrict__ nl) {
    int idx = blockIdx.x * 256 + threadIdx.x;
    if (idx < 1572864) {
        wb[idx] = f2us(w_lin1[idx]);
    } else if (idx < 5767168) {
        int d = idx - 1572864;
        int i2 = d & 1023, dk = (d >> 10) & 3, o = d >> 12;
        wb[idx] = f2us(w_conv[(size_t)o * 4096 + i2 * 4 + dk]);
    } else if (idx < 7864320) {
        wb[idx] = f2us(w_rg[idx - 5767168]);
    } else if (idx < 8650752) {
        wb[idx] = f2us(w_out[idx - 7864320]);
    } else if (idx < 13369344) {
        wb[idx] = f2us(w_m1[idx - 8650752]);
    } else if (idx < 15728640) {
        wb[idx] = f2us(w_m2[idx - 13369344]);
    } else {
        int c = idx - 15728640;
        if (c < D_RNN) nl[c] = -8.0f * log1pf(expf(Lambda[c]));
    }
}

// ---------------------------------------------------------------------------
// RMSNorm fp32 in -> bf16 out
// ---------------------------------------------------------------------------
__global__ __launch_bounds__(256) void rms_kernel(const float* __restrict__ x,
                                                  const float* __restrict__ w,
                                                  ushort_t* __restrict__ o, int D) {
    int row = blockIdx.x;
    const float* xr = x + (size_t)row * D;
    float ss = 0.0f;
    for (int i = threadIdx.x; i < D; i += 256) { float v = xr[i]; ss += v * v; }
    for (int off = 32; off > 0; off >>= 1) ss += __shfl_down(ss, off);
    __shared__ float wsum[4];
    __shared__ float sc;
    int lane = threadIdx.x & 63, wid = threadIdx.x >> 6;
    if (lane == 0) wsum[wid] = ss;
    __syncthreads();
    if (threadIdx.x == 0) {
        float t = wsum[0] + wsum[1] + wsum[2] + wsum[3];
        sc = rsqrtf(t / (float)D + 1e-5f);
    }
    __syncthreads();
    float s = sc;
    ushort_t* orow = o + (size_t)row * D;
    for (int i = threadIdx.x; i < D; i += 256) orow[i] = f2us(xr[i] * s * w[i]);
}

// ---------------------------------------------------------------------------
// MFMA bf16 NT GEMM, 128xBN_ tile, 4 waves (2x2), BK=32.
// Grid: blockIdx.x = m-block (fast dim -> same-A blocks share XCD L2),
//       blockIdx.y = n-block.
// AMODE 0: A[M,K] bf16 row-major.
// AMODE 1: conv im2col: element (m,k) = abb[(m + k/1024 - 3), k%1024]
//          == linear load at (m0+r-3)*1024 + k, guarded for m0==0.
// EMODE 0: bf16 -> Cb[M,N]
// EMODE 1: +bias, split halves -> Cb (n<1024), Cb2 (n>=1024), stride 1024
// EMODE 2: +bias +resid -> fp32 Cf[M,N]
// EMODE 3: dual-B gates -> bf16 a=Cb, gx=Cb2 (stride 1024)
// EMODE 4: dual-B geglu: Cb[m*3072+n] = gelu(acc1+b1)*(acc2+b2)
// ---------------------------------------------------------------------------
template <int BN_, int AMODE, int EMODE>
__global__ __launch_bounds__(256) void mfma_nt(const ushort_t* __restrict__ A,
                                               const ushort_t* __restrict__ B,
                                               const ushort_t* __restrict__ B2,
                                               const float* __restrict__ bias,
                                               const float* __restrict__ bias2,
                                               const float* __restrict__ resid,
                                               const float* __restrict__ nl,
                                               const ushort_t* __restrict__ cv,
                                               float* __restrict__ Cf,
                                               ushort_t* __restrict__ Cb,
                                               ushort_t* __restrict__ Cb2,
                                               int M, int N, int K) {
    constexpr bool DUAL = (EMODE == 3 || EMODE == 4);
    constexpr int NT = BN_ / 32;           // n-tiles per wave
    __shared__ ushort_t As[128 * 32];
    __shared__ ushort_t Bs[BN_ * 32];
    __shared__ ushort_t B2s[DUAL ? BN_ * 32 : 8];

    int tid = threadIdx.x;
    int wave = tid >> 6, lane = tid & 63;
    int quad = lane >> 4, l16 = lane & 15;
    int wm = (wave >> 1) * 64, wn = (wave & 1) * (BN_ / 2);
    int m0 = blockIdx.x * 128, n0 = blockIdx.y * BN_;   // XCD-swizzled mapping
    int r4 = tid >> 2;          // staging row 0..63
    int c8 = (tid & 3) * 8;     // staging k-offset

    const ushort_t* gA0;
    if (AMODE == 0) gA0 = A + (size_t)(m0 + r4) * K + c8;
    else            gA0 = A + ((size_t)(m0 + r4) - 3) * 1024 + c8; // shifted conv base
    const ushort_t* gA1 = gA0 + (size_t)64 * (AMODE == 0 ? K : 1024);
    const ushort_t* gB0 = B + (size_t)(n0 + r4) * K + c8;
    const ushort_t* gB1 = gB0 + (size_t)64 * K;
    const ushort_t* gB2 = DUAL ? (B2 + (size_t)(n0 + r4) * K + c8) : nullptr;

    f32x4 acc[4][NT] = {};
    f32x4 acc2[DUAL ? 4 : 1][DUAL ? NT : 1] = {};

    for (int k0 = 0; k0 < K; k0 += 32) {
        bool conv_guard = (AMODE == 1) && (m0 == 0);
#if HAS_ASYNC
        if (!conv_guard) {
            cp16(gA0 + k0, &As[wave * 512]);
            cp16(gA1 + k0, &As[wave * 512 + 2048]);
        } else
#endif
        {
            if (AMODE == 1 && m0 == 0) {
                int kglob = k0 + c8;
                int dk = kglob >> 10, ii = kglob & 1023;
                uint4 v0 = {0, 0, 0, 0};
                if (r4 + dk >= 3)
                    v0 = *(const uint4*)(A + (size_t)(r4 + dk - 3) * 1024 + ii);
                *(uint4*)&As[8 * tid] = v0;
                *(uint4*)&As[8 * tid + 2048] =
                    *(const uint4*)(A + (size_t)(r4 + 64 + dk - 3) * 1024 + ii);
            } else {
                *(uint4*)&As[8 * tid] = *(const uint4*)(gA0 + k0);
                *(uint4*)&As[8 * tid + 2048] = *(const uint4*)(gA1 + k0);
            }
        }
#if HAS_ASYNC
        cp16(gB0 + k0, &Bs[wave * 512]);
        if (BN_ == 128) cp16(gB1 + k0, &Bs[wave * 512 + 2048]);
        if constexpr (DUAL) cp16(gB2 + k0, &B2s[wave * 512]);
#else
        *(uint4*)&Bs[8 * tid] = *(const uint4*)(gB0 + k0);
        if (BN_ == 128) *(uint4*)&Bs[8 * tid + 2048] = *(const uint4*)(gB1 + k0);
        if constexpr (DUAL) *(uint4*)&B2s[8 * tid] = *(const uint4*)(gB2 + k0);
#endif
        __syncthreads();
        bf16x8 af[4], bfv[NT], bf2v[NT];
#pragma unroll
        for (int i = 0; i < 4; i++)
            af[i] = *(const bf16x8*)&As[(wm + i * 16 + l16) * 32 + quad * 8];
#pragma unroll
        for (int j = 0; j < NT; j++) {
            bfv[j] = *(const bf16x8*)&Bs[(wn + j * 16 + l16) * 32 + quad * 8];
            if constexpr (DUAL)
                bf2v[j] = *(const bf16x8*)&B2s[(wn + j * 16 + l16) * 32 + quad * 8];
        }
#pragma unroll
        for (int i = 0; i < 4; i++)
#pragma unroll
            for (int j = 0; j < NT; j++) {
                acc[i][j] = __builtin_amdgcn_mfma_f32_16x16x32_bf16(af[i], bfv[j],
                                                                   acc[i][j], 0, 0, 0);
                if constexpr (DUAL)
                    acc2[i][j] = __builtin_amdgcn_mfma_f32_16x16x32_bf16(af[i], bf2v[j],
                                                                        acc2[i][j], 0, 0, 0);
            }
        __syncthreads();
    }

    // ---- epilogue: C/D layout col=lane&15, row=quad*4+reg ----
#pragma unroll
    for (int i = 0; i < 4; i++) {
        int mb = m0 + wm + i * 16 + quad * 4;
#pragma unroll
        for (int j = 0; j < NT; j++) {
            int n = n0 + wn + j * 16 + l16;
#pragma unroll
            for (int rg = 0; rg < 4; rg++) {
                int m = mb + rg;
                float v = acc[i][j][rg];
                if constexpr (EMODE == 0) {
                    Cb[(size_t)m * N + n] = f2us(v);
                } else if constexpr (EMODE == 1) {
                    v += bias[n];
                    if (n < 1024) Cb[((size_t)m << 10) + n] = f2us(v);
                    else          Cb2[((size_t)m << 10) + (n - 1024)] = f2us(v);
                } else if constexpr (EMODE == 2) {
                    v += bias[n];
                    if (resid) v += resid[(size_t)m * N + n];
                    Cf[(size_t)m * N + n] = v;
                } else if constexpr (EMODE == 3) {
                    float ig = sigmoidf_(v + bias[n]);
                    float rgv = sigmoidf_(acc2[i][j][rg] + bias2[n]);
                    float av = expf(nl[n] * rgv);
                    size_t id = ((size_t)m << 10) + n;
                    Cb[id] = f2us(av);
                    Cb2[id] = f2us(sqrtf(fmaxf(1.0f - av * av, 0.0f)) * ig * us2f(cv[id]));
                } else { // EMODE 4
                    float v1 = gelu_tanh(v + bias[n]);
                    float v2 = acc2[i][j][rg] + bias2[n];
                    Cb[(size_t)m * 3072 + n] = f2us(v1 * v2);
                }
            }
        }
    }
}

// ---------------------------------------------------------------------------
// Chunked linear scan over bf16 a/gx: h_t = a_t*h_{t-1} + gx_t.
// 64 chunks x 128 steps. Pass 3 fuses z = gelu(aba)*h (bf16 out).
// ---------------------------------------------------------------------------
#define NCHUNK 64
#define CHLEN 128

__global__ __launch_bounds__(256) void scan_pass1(const ushort_t* __restrict__ a16,
                                                  const ushort_t* __restrict__ g16,
                                                  float* __restrict__ Ac,
                                                  float* __restrict__ Bc) {
    int g = blockIdx.x * 256 + threadIdx.x; // 65536
    int ch = g & 1023, ck = g >> 10;
    float P = 1.0f, Bv = 0.0f;
    size_t base = (((size_t)ck * CHLEN) << 10) + ch;
#pragma unroll 8
    for (int t = 0; t < CHLEN; t++) {
        size_t id = base + ((size_t)t << 10);
        float av = us2f(a16[id]);
        float bv = us2f(g16[id]);
        P *= av;
        Bv = av * Bv + bv;
    }
    Ac[ck * 1024 + ch] = P;
    Bc[ck * 1024 + ch] = Bv;
}

__global__ __launch_bounds__(256) void scan_pass2(const float* __restrict__ Ac,
                                                  const float* __restrict__ Bc,
                                                  float* __restrict__ Hc) {
    int ch = blockIdx.x * 256 + threadIdx.x; // 1024
    float H = 0.0f;
#pragma unroll 8
    for (int j = 0; j < NCHUNK; j++) {
        Hc[j * 1024 + ch] = H;
        H = Ac[j * 1024 + ch] * H + Bc[j * 1024 + ch];
    }
}

__global__ __launch_bounds__(256) void scan_pass3(const ushort_t* __restrict__ a16,
                                                  const ushort_t* __restrict__ g16,
                                                  const float* __restrict__ Hc,
                                                  const ushort_t* __restrict__ aba,
                                                  ushort_t* __restrict__ z) {
    int g = blockIdx.x * 256 + threadIdx.x;
    int ch = g & 1023, ck = g >> 10;
    float state = Hc[ck * 1024 + ch];
    size_t base = (((size_t)ck * CHLEN) << 10) + ch;
#pragma unroll 8
    for (int t = 0; t < CHLEN; t++) {
        size_t id = base + ((size_t)t << 10);
        state = fmaf(us2f(a16[id]), state, us2f(g16[id]));
        z[id] = f2us(gelu_tanh(us2f(aba[id])) * state);
    }
}

// ---------------------------------------------------------------------------
extern "C" void kernel_launch(void* const* d_in, const int* in_sizes, int n_in,
                              void* d_out, int out_size, void* d_ws, size_t ws_size,
                              hipStream_t stream) {
    const float* x      = (const float*)d_in[0];
    const float* w_n1   = (const float*)d_in[1];
    const float* w_n2   = (const float*)d_in[2];
    const float* w_lin1 = (const float*)d_in[3];
    const float* b_lin1 = (const float*)d_in[4];
    const float* w_conv = (const float*)d_in[5];
    const float* w_rg   = (const float*)d_in[6];
    const float* b_rg   = (const float*)d_in[7];
    const float* Lambda = (const float*)d_in[8];
    const float* w_out  = (const float*)d_in[9];
    const float* b_out  = (const float*)d_in[10];
    const float* w_m1   = (const float*)d_in[11];
    const float* b_m1   = (const float*)d_in[12];
    const float* w_m2   = (const float*)d_in[13];
    const float* b_m2   = (const float*)d_in[14];

    char* ws = (char*)d_ws;
    const size_t MB = 1024ull * 1024ull;
    // Peak footprint 182 MB (<208 proven safe).
    // [0,32)    wb bf16 weights (persistent)
    // [32,56)   x1 fp32
    // [56,+4K)  nl
    // [57,69)   h16 / h2 (12 MB)
    // [69,85)   aba 16 MB (dead after pass3)
    // [85,101)  abb 16 MB (dead after conv) -> z16 (pass3 output)
    // [101,117) cv16 16 MB (dead after gates)
    // [117,133) a16 16 MB; [133,149) gx16 16 MB   (S*1024*2B each! dead after pass3)
    //           -> gm [117,165) 48 MB (geglu output, written step 8)
    // [181,182) Ac, Bc, Hc (256 KB each)
    ushort_t* wb   = (ushort_t*)(ws + 0);
    float*    x1   = (float*)(ws + 32 * MB);
    float*    nl   = (float*)(ws + 56 * MB);
    ushort_t* h16  = (ushort_t*)(ws + 57 * MB);
    ushort_t* aba  = (ushort_t*)(ws + 69 * MB);
    ushort_t* abb  = (ushort_t*)(ws + 85 * MB);
    ushort_t* z16  = (ushort_t*)(ws + 85 * MB);
    ushort_t* cv16 = (ushort_t*)(ws + 101 * MB);
    ushort_t* a16  = (ushort_t*)(ws + 117 * MB);
    ushort_t* gx16 = (ushort_t*)(ws + 133 * MB);
    ushort_t* gm   = (ushort_t*)(ws + 117 * MB);
    float*    Ac   = (float*)(ws + 181 * MB);
    float*    Bc   = (float*)(ws + 181 * MB + 262144);
    float*    Hc   = (float*)(ws + 181 * MB + 524288);
    float*    out  = (float*)d_out;

    ushort_t* wb_lin1 = wb + 0;          // 2048*768
    ushort_t* wb_conv = wb + 1572864;    // 1024*4096 (reordered)
    ushort_t* wb_rg   = wb + 5767168;    // 2048*1024
    ushort_t* wb_out  = wb + 7864320;    // 768*1024
    ushort_t* wb_m1   = wb + 8650752;    // 6144*768
    ushort_t* wb_m2   = wb + 13369344;   // 768*3072

    const int M = S_LEN;

    // 0. all weight conversions + nl in one launch
    cvt_all<<<61444, 256, 0, stream>>>(w_lin1, w_conv, w_rg, w_out, w_m1, w_m2,
                                       Lambda, wb, nl);
    // 1. h = rms(x, w_n1)
    rms_kernel<<<M, 256, 0, stream>>>(x, w_n1, h16, D_MODEL);
    // 2. ab = h @ w_lin1^T + b_lin1, split -> aba/abb  (N=2048, K=768)
    mfma_nt<128, 0, 1><<<dim3(M / 128, 2048 / 128), 256, 0, stream>>>(
        h16, wb_lin1, nullptr, b_lin1, nullptr, nullptr, nullptr, nullptr,
        nullptr, aba, abb, M, 2048, 768);
    // 3. conv = im2col(abb) @ wb_conv^T -> cv16  (N=1024, K=4096, fused gather)
    mfma_nt<128, 1, 0><<<dim3(M / 128, 1024 / 128), 256, 0, stream>>>(
        abb, wb_conv, nullptr, nullptr, nullptr, nullptr, nullptr, nullptr,
        nullptr, cv16, nullptr, M, 1024, 4096);
    // 4. dual-B gates GEMM + gate math -> a16, gx16 bf16  (N'=1024, K=1024)
    mfma_nt<64, 0, 3><<<dim3(M / 128, 1024 / 64), 256, 0, stream>>>(
        cv16, wb_rg, wb_rg + 1024 * 1024, b_rg, b_rg + 1024, nullptr, nl, cv16,
        nullptr, a16, gx16, M, 1024, 1024);
    // 5. chunked scan; pass3 fuses z = gelu(aba)*h -> z16
    scan_pass1<<<256, 256, 0, stream>>>(a16, gx16, Ac, Bc);
    scan_pass2<<<4, 256, 0, stream>>>(Ac, Bc, Hc);
    scan_pass3<<<256, 256, 0, stream>>>(a16, gx16, Hc, aba, z16);
    // 6. x1 = z @ w_out^T + b_out + x  (N=768, K=1024, fp32)
    mfma_nt<64, 0, 2><<<dim3(M / 128, 768 / 64), 256, 0, stream>>>(
        z16, wb_out, nullptr, b_out, nullptr, x, nullptr, nullptr,
        x1, nullptr, nullptr, M, 768, 1024);
    // 7. h2 = rms(x1, w_n2)
    rms_kernel<<<M, 256, 0, stream>>>(x1, w_n2, h16, D_MODEL);
    // 8. dual-B MLP up-proj + GeGLU -> gm bf16  (N'=3072, K=768)
    mfma_nt<64, 0, 4><<<dim3(M / 128, 3072 / 64), 256, 0, stream>>>(
        h16, wb_m1, wb_m1 + 3072 * 768, b_m1, b_m1 + 3072, nullptr, nullptr, nullptr,
        nullptr, gm, nullptr, M, 3072, 768);
    // 9. out = gm @ w_m2^T + b_m2 + x1  (N=768, K=3072, fp32)
    mfma_nt<64, 0, 2><<<dim3(M / 128, 768 / 64), 256, 0, stream>>>(
        gm, wb_m2, nullptr, b_m2, nullptr, x1, nullptr, nullptr,
        out, nullptr, nullptr, M, 768, 3072);
}

// Round 9
// 645.146 us; speedup vs baseline: 8.9969x; 1.0841x over previous
//
#include <hip/hip_runtime.h>
#include <hip/hip_bf16.h>
#include <math.h>

#define S_LEN 8192
#define D_MODEL 768
#define D_RNN 1024
#define MLP_INNER 3072

typedef __attribute__((ext_vector_type(8))) short bf16x8;
typedef __attribute__((ext_vector_type(4))) float f32x4;
typedef unsigned short ushort_t;

#ifndef __has_builtin
#define __has_builtin(x) 0
#endif
#if __has_builtin(__builtin_amdgcn_global_load_lds)
#define HAS_ASYNC 1
#else
#define HAS_ASYNC 0
#endif

#define LOG2E 1.4426950408889634f

// fast sigmoid: 1/(1+2^(-x*log2e)); v_exp_f32 + v_rcp_f32, ~1ulp
__device__ __forceinline__ float fast_sigmoid(float x) {
    float e = __builtin_amdgcn_exp2f(-x * LOG2E);
    return __builtin_amdgcn_rcpf(1.0f + e);
}
// fast exp
__device__ __forceinline__ float fast_exp(float x) {
    return __builtin_amdgcn_exp2f(x * LOG2E);
}
// gelu(tanh approx) = v * sigmoid(2*0.7978845608*(v + 0.044715 v^3))
__device__ __forceinline__ float gelu_fast(float v) {
    float u = v * (1.5957691216057308f + 0.07135481283247183f * v * v);
    return v * fast_sigmoid(u);
}
__device__ __forceinline__ float us2f(ushort_t u) { return __uint_as_float(((unsigned)u) << 16); }
__device__ __forceinline__ ushort_t f2us(float f) {
    __hip_bfloat16 b = __float2bfloat16(f);
    return *(ushort_t*)&b;
}

// async 16B global -> LDS (wave-uniform LDS base; HW adds lane*16B)
__device__ __forceinline__ void cp16(const ushort_t* g, ushort_t* l) {
#if HAS_ASYNC
    __builtin_amdgcn_global_load_lds((__attribute__((address_space(1))) void*)g,
                                     (__attribute__((address_space(3))) void*)l,
                                     16, 0, 0);
#endif
}

// ---------------------------------------------------------------------------
// One-shot weight conversion fp32 -> bf16 (all weights) + nl
// ---------------------------------------------------------------------------
__global__ __launch_bounds__(256) void cvt_all(const float* __restrict__ w_lin1,
                                               const float* __restrict__ w_conv,
                                               const float* __restrict__ w_rg,
                                               const float* __restrict__ w_out,
                                               const float* __restrict__ w_m1,
                                               const float* __restrict__ w_m2,
                                               const float* __restrict__ Lambda,
                                               ushort_t* __restrict__ wb,
                                               float* __restrict__ nl) {
    int idx = blockIdx.x * 256 + threadIdx.x;
    if (idx < 1572864) {
        wb[idx] = f2us(w_lin1[idx]);
    } else if (idx < 5767168) {
        int d = idx - 1572864;
        int i2 = d & 1023, dk = (d >> 10) & 3, o = d >> 12;
        wb[idx] = f2us(w_conv[(size_t)o * 4096 + i2 * 4 + dk]);
    } else if (idx < 7864320) {
        wb[idx] = f2us(w_rg[idx - 5767168]);
    } else if (idx < 8650752) {
        wb[idx] = f2us(w_out[idx - 7864320]);
    } else if (idx < 13369344) {
        wb[idx] = f2us(w_m1[idx - 8650752]);
    } else if (idx < 15728640) {
        wb[idx] = f2us(w_m2[idx - 13369344]);
    } else {
        int c = idx - 15728640;
        if (c < D_RNN) nl[c] = -8.0f * log1pf(expf(Lambda[c]));
    }
}

// ---------------------------------------------------------------------------
// RMSNorm fp32 in -> bf16 out
// ---------------------------------------------------------------------------
__global__ __launch_bounds__(256) void rms_kernel(const float* __restrict__ x,
                                                  const float* __restrict__ w,
                                                  ushort_t* __restrict__ o, int D) {
    int row = blockIdx.x;
    const float* xr = x + (size_t)row * D;
    float ss = 0.0f;
    for (int i = threadIdx.x; i < D; i += 256) { float v = xr[i]; ss += v * v; }
    for (int off = 32; off > 0; off >>= 1) ss += __shfl_down(ss, off);
    __shared__ float wsum[4];
    __shared__ float sc;
    int lane = threadIdx.x & 63, wid = threadIdx.x >> 6;
    if (lane == 0) wsum[wid] = ss;
    __syncthreads();
    if (threadIdx.x == 0) {
        float t = wsum[0] + wsum[1] + wsum[2] + wsum[3];
        sc = rsqrtf(t / (float)D + 1e-5f);
    }
    __syncthreads();
    float s = sc;
    ushort_t* orow = o + (size_t)row * D;
    for (int i = threadIdx.x; i < D; i += 256) orow[i] = f2us(xr[i] * s * w[i]);
}

// ---------------------------------------------------------------------------
// MFMA bf16 NT GEMM, 128xBN_ tile, 4 waves (2x2), BK=32.
// Grid: blockIdx.x = m-block (fast dim: same-A blocks share XCD L2).
// LDS layout XOR-swizzled: row r stores k-chunk c (16B) at slot c^(r&3).
// Staging keeps global coalescing (lane permutation within a 64B row span)
// and global_load_lds lane-contiguity. Fragment reads use chunk quad^(l16&3).
// AMODE 0: A[M,K] bf16 row-major.
// AMODE 1: conv im2col: element (m,k) = abb[(m-3)*1024 + k] (linear),
//          guarded for m0==0.
// EMODE 0: bf16 -> Cb[M,N]
// EMODE 1: +bias, split halves -> Cb (n<1024), Cb2 (n>=1024), stride 1024
// EMODE 2: +bias +resid -> fp32 Cf[M,N]
// EMODE 3: dual-B gates -> bf16 a=Cb, gx=Cb2 (stride 1024)
// EMODE 4: dual-B geglu: Cb[m*3072+n] = gelu(acc1+b1)*(acc2+b2)
// ---------------------------------------------------------------------------
template <int BN_, int AMODE, int EMODE>
__global__ __launch_bounds__(256) void mfma_nt(const ushort_t* __restrict__ A,
                                               const ushort_t* __restrict__ B,
                                               const ushort_t* __restrict__ B2,
                                               const float* __restrict__ bias,
                                               const float* __restrict__ bias2,
                                               const float* __restrict__ resid,
                                               const float* __restrict__ nl,
                                               const ushort_t* __restrict__ cv,
                                               float* __restrict__ Cf,
                                               ushort_t* __restrict__ Cb,
                                               ushort_t* __restrict__ Cb2,
                                               int M, int N, int K) {
    constexpr bool DUAL = (EMODE == 3 || EMODE == 4);
    constexpr int NT = BN_ / 32;           // n-tiles per wave
    __shared__ ushort_t As[128 * 32];
    __shared__ ushort_t Bs[BN_ * 32];
    __shared__ ushort_t B2s[DUAL ? BN_ * 32 : 8];

    int tid = threadIdx.x;
    int wave = tid >> 6, lane = tid & 63;
    int quad = lane >> 4, l16 = lane & 15;
    int wm = (wave >> 1) * 64, wn = (wave & 1) * (BN_ / 2);
    int m0 = blockIdx.x * 128, n0 = blockIdx.y * BN_;
    int r4 = tid >> 2;                       // staging row 0..63
    int c8 = (((tid & 3) ^ (r4 & 3)) * 8);   // XOR-swizzled staging k-offset

    const ushort_t* gA0;
    if (AMODE == 0) gA0 = A + (size_t)(m0 + r4) * K + c8;
    else            gA0 = A + ((size_t)(m0 + r4) - 3) * 1024 + c8; // shifted conv base
    const ushort_t* gA1 = gA0 + (size_t)64 * (AMODE == 0 ? K : 1024);
    const ushort_t* gB0 = B + (size_t)(n0 + r4) * K + c8;
    const ushort_t* gB1 = gB0 + (size_t)64 * K;
    const ushort_t* gB2 = DUAL ? (B2 + (size_t)(n0 + r4) * K + c8) : nullptr;

    f32x4 acc[4][NT] = {};
    f32x4 acc2[DUAL ? 4 : 1][DUAL ? NT : 1] = {};

    for (int k0 = 0; k0 < K; k0 += 32) {
        bool conv_guard = (AMODE == 1) && (m0 == 0);
#if HAS_ASYNC
        if (!conv_guard) {
            cp16(gA0 + k0, &As[wave * 512]);
            cp16(gA1 + k0, &As[wave * 512 + 2048]);
        } else
#endif
        {
            if (AMODE == 1 && m0 == 0) {
                int kglob = k0 + c8;
                int dk = kglob >> 10, ii = kglob & 1023;
                uint4 v0 = {0, 0, 0, 0};
                if (r4 + dk >= 3)
                    v0 = *(const uint4*)(A + (size_t)(r4 + dk - 3) * 1024 + ii);
                *(uint4*)&As[8 * tid] = v0;
                *(uint4*)&As[8 * tid + 2048] =
                    *(const uint4*)(A + (size_t)(r4 + 64 + dk - 3) * 1024 + ii);
            } else {
                *(uint4*)&As[8 * tid] = *(const uint4*)(gA0 + k0);
                *(uint4*)&As[8 * tid + 2048] = *(const uint4*)(gA1 + k0);
            }
        }
#if HAS_ASYNC
        cp16(gB0 + k0, &Bs[wave * 512]);
        if (BN_ == 128) cp16(gB1 + k0, &Bs[wave * 512 + 2048]);
        if constexpr (DUAL) cp16(gB2 + k0, &B2s[wave * 512]);
#else
        *(uint4*)&Bs[8 * tid] = *(const uint4*)(gB0 + k0);
        if (BN_ == 128) *(uint4*)&Bs[8 * tid + 2048] = *(const uint4*)(gB1 + k0);
        if constexpr (DUAL) *(uint4*)&B2s[8 * tid] = *(const uint4*)(gB2 + k0);
#endif
        __syncthreads();
        bf16x8 af[4], bfv[NT], bf2v[NT];
        int ksw = ((quad ^ (l16 & 3)) << 3);   // XOR-swizzled fragment k-offset
#pragma unroll
        for (int i = 0; i < 4; i++)
            af[i] = *(const bf16x8*)&As[(wm + i * 16 + l16) * 32 + ksw];
#pragma unroll
        for (int j = 0; j < NT; j++) {
            bfv[j] = *(const bf16x8*)&Bs[(wn + j * 16 + l16) * 32 + ksw];
            if constexpr (DUAL)
                bf2v[j] = *(const bf16x8*)&B2s[(wn + j * 16 + l16) * 32 + ksw];
        }
#pragma unroll
        for (int i = 0; i < 4; i++)
#pragma unroll
            for (int j = 0; j < NT; j++) {
                acc[i][j] = __builtin_amdgcn_mfma_f32_16x16x32_bf16(af[i], bfv[j],
                                                                   acc[i][j], 0, 0, 0);
                if constexpr (DUAL)
                    acc2[i][j] = __builtin_amdgcn_mfma_f32_16x16x32_bf16(af[i], bf2v[j],
                                                                        acc2[i][j], 0, 0, 0);
            }
        __syncthreads();
    }

    // ---- epilogue: C/D layout col=lane&15, row=quad*4+reg ----
#pragma unroll
    for (int i = 0; i < 4; i++) {
        int mb = m0 + wm + i * 16 + quad * 4;
#pragma unroll
        for (int j = 0; j < NT; j++) {
            int n = n0 + wn + j * 16 + l16;
#pragma unroll
            for (int rg = 0; rg < 4; rg++) {
                int m = mb + rg;
                float v = acc[i][j][rg];
                if constexpr (EMODE == 0) {
                    Cb[(size_t)m * N + n] = f2us(v);
                } else if constexpr (EMODE == 1) {
                    v += bias[n];
                    if (n < 1024) Cb[((size_t)m << 10) + n] = f2us(v);
                    else          Cb2[((size_t)m << 10) + (n - 1024)] = f2us(v);
                } else if constexpr (EMODE == 2) {
                    v += bias[n];
                    if (resid) v += resid[(size_t)m * N + n];
                    Cf[(size_t)m * N + n] = v;
                } else if constexpr (EMODE == 3) {
                    float ig = fast_sigmoid(v + bias[n]);
                    float rgv = fast_sigmoid(acc2[i][j][rg] + bias2[n]);
                    float av = fast_exp(nl[n] * rgv);
                    size_t id = ((size_t)m << 10) + n;
                    Cb[id] = f2us(av);
                    Cb2[id] = f2us(sqrtf(fmaxf(1.0f - av * av, 0.0f)) * ig * us2f(cv[id]));
                } else { // EMODE 4
                    float v1 = gelu_fast(v + bias[n]);
                    float v2 = acc2[i][j][rg] + bias2[n];
                    Cb[(size_t)m * 3072 + n] = f2us(v1 * v2);
                }
            }
        }
    }
}

// ---------------------------------------------------------------------------
// Chunked linear scan over bf16 a/gx: h_t = a_t*h_{t-1} + gx_t.
// 64 chunks x 128 steps. Pass 3 fuses z = gelu(aba)*h (bf16 out).
// ---------------------------------------------------------------------------
#define NCHUNK 64
#define CHLEN 128

__global__ __launch_bounds__(256) void scan_pass1(const ushort_t* __restrict__ a16,
                                                  const ushort_t* __restrict__ g16,
                                                  float* __restrict__ Ac,
                                                  float* __restrict__ Bc) {
    int g = blockIdx.x * 256 + threadIdx.x; // 65536
    int ch = g & 1023, ck = g >> 10;
    float P = 1.0f, Bv = 0.0f;
    size_t base = (((size_t)ck * CHLEN) << 10) + ch;
#pragma unroll 8
    for (int t = 0; t < CHLEN; t++) {
        size_t id = base + ((size_t)t << 10);
        float av = us2f(a16[id]);
        float bv = us2f(g16[id]);
        P *= av;
        Bv = av * Bv + bv;
    }
    Ac[ck * 1024 + ch] = P;
    Bc[ck * 1024 + ch] = Bv;
}

__global__ __launch_bounds__(256) void scan_pass2(const float* __restrict__ Ac,
                                                  const float* __restrict__ Bc,
                                                  float* __restrict__ Hc) {
    int ch = blockIdx.x * 256 + threadIdx.x; // 1024
    float H = 0.0f;
#pragma unroll 8
    for (int j = 0; j < NCHUNK; j++) {
        Hc[j * 1024 + ch] = H;
        H = Ac[j * 1024 + ch] * H + Bc[j * 1024 + ch];
    }
}

__global__ __launch_bounds__(256) void scan_pass3(const ushort_t* __restrict__ a16,
                                                  const ushort_t* __restrict__ g16,
                                                  const float* __restrict__ Hc,
                                                  const ushort_t* __restrict__ aba,
                                                  ushort_t* __restrict__ z) {
    int g = blockIdx.x * 256 + threadIdx.x;
    int ch = g & 1023, ck = g >> 10;
    float state = Hc[ck * 1024 + ch];
    size_t base = (((size_t)ck * CHLEN) << 10) + ch;
#pragma unroll 8
    for (int t = 0; t < CHLEN; t++) {
        size_t id = base + ((size_t)t << 10);
        state = fmaf(us2f(a16[id]), state, us2f(g16[id]));
        z[id] = f2us(gelu_fast(us2f(aba[id])) * state);
    }
}

// ---------------------------------------------------------------------------
extern "C" void kernel_launch(void* const* d_in, const int* in_sizes, int n_in,
                              void* d_out, int out_size, void* d_ws, size_t ws_size,
                              hipStream_t stream) {
    const float* x      = (const float*)d_in[0];
    const float* w_n1   = (const float*)d_in[1];
    const float* w_n2   = (const float*)d_in[2];
    const float* w_lin1 = (const float*)d_in[3];
    const float* b_lin1 = (const float*)d_in[4];
    const float* w_conv = (const float*)d_in[5];
    const float* w_rg   = (const float*)d_in[6];
    const float* b_rg   = (const float*)d_in[7];
    const float* Lambda = (const float*)d_in[8];
    const float* w_out  = (const float*)d_in[9];
    const float* b_out  = (const float*)d_in[10];
    const float* w_m1   = (const float*)d_in[11];
    const float* b_m1   = (const float*)d_in[12];
    const float* w_m2   = (const float*)d_in[13];
    const float* b_m2   = (const float*)d_in[14];

    char* ws = (char*)d_ws;
    const size_t MB = 1024ull * 1024ull;
    // Peak footprint 182 MB (<208 proven safe).
    // [0,32)    wb bf16 weights (persistent)
    // [32,56)   x1 fp32
    // [56,+4K)  nl
    // [57,69)   h16 / h2 (12 MB)
    // [69,85)   aba 16 MB (dead after pass3)
    // [85,101)  abb 16 MB (dead after conv) -> z16 (pass3 output)
    // [101,117) cv16 16 MB (dead after gates)
    // [117,133) a16 16 MB; [133,149) gx16 16 MB (dead after pass3)
    //           -> gm [117,165) 48 MB (geglu output, written step 8)
    // [181,182) Ac, Bc, Hc (256 KB each)
    ushort_t* wb   = (ushort_t*)(ws + 0);
    float*    x1   = (float*)(ws + 32 * MB);
    float*    nl   = (float*)(ws + 56 * MB);
    ushort_t* h16  = (ushort_t*)(ws + 57 * MB);
    ushort_t* aba  = (ushort_t*)(ws + 69 * MB);
    ushort_t* abb  = (ushort_t*)(ws + 85 * MB);
    ushort_t* z16  = (ushort_t*)(ws + 85 * MB);
    ushort_t* cv16 = (ushort_t*)(ws + 101 * MB);
    ushort_t* a16  = (ushort_t*)(ws + 117 * MB);
    ushort_t* gx16 = (ushort_t*)(ws + 133 * MB);
    ushort_t* gm   = (ushort_t*)(ws + 117 * MB);
    float*    Ac   = (float*)(ws + 181 * MB);
    float*    Bc   = (float*)(ws + 181 * MB + 262144);
    float*    Hc   = (float*)(ws + 181 * MB + 524288);
    float*    out  = (float*)d_out;

    ushort_t* wb_lin1 = wb + 0;          // 2048*768
    ushort_t* wb_conv = wb + 1572864;    // 1024*4096 (reordered)
    ushort_t* wb_rg   = wb + 5767168;    // 2048*1024
    ushort_t* wb_out  = wb + 7864320;    // 768*1024
    ushort_t* wb_m1   = wb + 8650752;    // 6144*768
    ushort_t* wb_m2   = wb + 13369344;   // 768*3072

    const int M = S_LEN;

    // 0. all weight conversions + nl in one launch
    cvt_all<<<61444, 256, 0, stream>>>(w_lin1, w_conv, w_rg, w_out, w_m1, w_m2,
                                       Lambda, wb, nl);
    // 1. h = rms(x, w_n1)
    rms_kernel<<<M, 256, 0, stream>>>(x, w_n1, h16, D_MODEL);
    // 2. ab = h @ w_lin1^T + b_lin1, split -> aba/abb  (N=2048, K=768)
    mfma_nt<128, 0, 1><<<dim3(M / 128, 2048 / 128), 256, 0, stream>>>(
        h16, wb_lin1, nullptr, b_lin1, nullptr, nullptr, nullptr, nullptr,
        nullptr, aba, abb, M, 2048, 768);
    // 3. conv = im2col(abb) @ wb_conv^T -> cv16  (N=1024, K=4096, fused gather)
    mfma_nt<128, 1, 0><<<dim3(M / 128, 1024 / 128), 256, 0, stream>>>(
        abb, wb_conv, nullptr, nullptr, nullptr, nullptr, nullptr, nullptr,
        nullptr, cv16, nullptr, M, 1024, 4096);
    // 4. dual-B gates GEMM + gate math -> a16, gx16 bf16  (N'=1024, K=1024)
    mfma_nt<64, 0, 3><<<dim3(M / 128, 1024 / 64), 256, 0, stream>>>(
        cv16, wb_rg, wb_rg + 1024 * 1024, b_rg, b_rg + 1024, nullptr, nl, cv16,
        nullptr, a16, gx16, M, 1024, 1024);
    // 5. chunked scan; pass3 fuses z = gelu(aba)*h -> z16
    scan_pass1<<<256, 256, 0, stream>>>(a16, gx16, Ac, Bc);
    scan_pass2<<<4, 256, 0, stream>>>(Ac, Bc, Hc);
    scan_pass3<<<256, 256, 0, stream>>>(a16, gx16, Hc, aba, z16);
    // 6. x1 = z @ w_out^T + b_out + x  (N=768, K=1024, fp32)
    mfma_nt<64, 0, 2><<<dim3(M / 128, 768 / 64), 256, 0, stream>>>(
        z16, wb_out, nullptr, b_out, nullptr, x, nullptr, nullptr,
        x1, nullptr, nullptr, M, 768, 1024);
    // 7. h2 = rms(x1, w_n2)
    rms_kernel<<<M, 256, 0, stream>>>(x1, w_n2, h16, D_MODEL);
    // 8. dual-B MLP up-proj + GeGLU -> gm bf16  (N'=3072, K=768)
    mfma_nt<64, 0, 4><<<dim3(M / 128, 3072 / 64), 256, 0, stream>>>(
        h16, wb_m1, wb_m1 + 3072 * 768, b_m1, b_m1 + 3072, nullptr, nullptr, nullptr,
        nullptr, gm, nullptr, M, 3072, 768);
    // 9. out = gm @ w_m2^T + b_m2 + x1  (N=768, K=3072, fp32)
    mfma_nt<64, 0, 2><<<dim3(M / 128, 768 / 64), 256, 0, stream>>>(
        gm, wb_m2, nullptr, b_m2, nullptr, x1, nullptr, nullptr,
        out, nullptr, nullptr, M, 768, 3072);
}